// Round 1
// baseline (22678.548 us; speedup 1.0000x reference)
//
#include <hip/hip_runtime.h>
#include <hip/hip_cooperative_groups.h>

namespace cg = cooperative_groups;

#define NPTS   32768
#define NBLK   512
#define PPB    64     // points per block
#define SL     16     // hidden-slice per thread (4 slices x 16 = H)
#define HDIM   64
#define MAXSTEPS 24

__device__ __forceinline__ float fast_tanh(float x) {
    // tanh(x) = 1 - 2/(1+e^{2x}); exact saturation at +-inf, ~1e-7 abs error
    float e = __expf(2.0f * x);
    return fmaf(-2.0f, __builtin_amdgcn_rcpf(1.0f + e), 1.0f);
}

__global__ void __launch_bounds__(256, 2)
ode_dopri5(const float* __restrict__ yin,
           const float* __restrict__ W1, const float* __restrict__ b1,
           const float* __restrict__ W2, const float* __restrict__ b2,
           const float* __restrict__ W3, const float* __restrict__ b3,
           float* yout, float* part)
{
    __shared__ float h1s[PPB * 65];   // stride 65: conflict-free (65 == 1 mod 32)
    __shared__ float outp[PPB * 13];  // [point][slice*3+d], stride 13 (odd)
    __shared__ float red[PPB];

    cg::grid_group grid = cg::this_grid();

    const int tid   = threadIdx.x;
    const int p     = tid & 63;
    // wave-uniform slice id -> weight indices become SGPR addresses (s_load)
    const int slice = __builtin_amdgcn_readfirstlane((int)(tid >> 6));
    const int s16   = slice * SL;
    const int p65   = p * 65;
    const int p13   = p * 13;
    const int gp    = (int)blockIdx.x * PPB + p;

    float y0 = yin[3*gp+0], y1 = yin[3*gp+1], y2 = yin[3*gp+2];
    float t = 0.0f, dt = 0.05f;
    float ks[7][3];

    auto feval = [&](float ts, float yi0, float yi1, float yi2, float* kout) {
        // ---- layer 1: (y0,y1,y2,t) @ W1[4x64] + b1, tanh ----
        float h1v[SL];
        #pragma unroll
        for (int kk = 0; kk < SL; ++kk) {
            const int k = s16 + kk;
            float a = b1[k];
            a = fmaf(yi0, W1[k],          a);
            a = fmaf(yi1, W1[HDIM+k],     a);
            a = fmaf(yi2, W1[2*HDIM+k],   a);
            a = fmaf(ts,  W1[3*HDIM+k],   a);
            h1v[kk] = fast_tanh(a);
        }
        #pragma unroll
        for (int kk = 0; kk < SL; ++kk) h1s[p65 + s16 + kk] = h1v[kk];
        __syncthreads();
        // ---- layer 2: h1 @ W2[64x64] + b2, tanh (own 16 cols) ----
        float acc[SL];
        #pragma unroll
        for (int kk = 0; kk < SL; ++kk) acc[kk] = b2[s16 + kk];
        #pragma unroll 4
        for (int j = 0; j < HDIM; ++j) {
            const float hj = h1s[p65 + j];
            const float* __restrict__ w = W2 + j*HDIM + s16;   // wave-uniform
            #pragma unroll
            for (int kk = 0; kk < SL; ++kk) acc[kk] = fmaf(w[kk], hj, acc[kk]);
        }
        // ---- layer 3 partials: h2(own 16) @ W3[64x3] ----
        float po0 = 0.f, po1 = 0.f, po2 = 0.f;
        #pragma unroll
        for (int kk = 0; kk < SL; ++kk) {
            const float h2 = fast_tanh(acc[kk]);
            const float* __restrict__ w3 = W3 + 3*(s16+kk);
            po0 = fmaf(h2, w3[0], po0);
            po1 = fmaf(h2, w3[1], po1);
            po2 = fmaf(h2, w3[2], po2);
        }
        outp[p13 + 3*slice + 0] = po0;
        outp[p13 + 3*slice + 1] = po1;
        outp[p13 + 3*slice + 2] = po2;
        __syncthreads();
        // combine 4 slice-partials in fixed order (replicated, deterministic)
        float c0 = b3[0], c1 = b3[1], c2 = b3[2];
        #pragma unroll
        for (int s2 = 0; s2 < 4; ++s2) {
            c0 += outp[p13 + 3*s2 + 0];
            c1 += outp[p13 + 3*s2 + 1];
            c2 += outp[p13 + 3*s2 + 2];
        }
        kout[0] = c0; kout[1] = c1; kout[2] = c2;
    };

    for (int step = 0; step < MAXSTEPS; ++step) {
        const float remaining = 1.0f - t;
        if (remaining <= 1e-9f) break;           // inactive iters are exact no-ops
        const float dt_c = fminf(dt, remaining);

        // ---- 7 dopri5 stages ----
        feval(t, y0, y1, y2, ks[0]);
        {   const float a = dt_c * (float)(1.0/5.0);
            feval(fmaf((float)(1.0/5.0), dt_c, t),
                  fmaf(a, ks[0][0], y0), fmaf(a, ks[0][1], y1), fmaf(a, ks[0][2], y2), ks[1]); }
        {   const float a0 = dt_c*(float)(3.0/40.0), a1 = dt_c*(float)(9.0/40.0);
            float yi0 = fmaf(a1, ks[1][0], fmaf(a0, ks[0][0], y0));
            float yi1 = fmaf(a1, ks[1][1], fmaf(a0, ks[0][1], y1));
            float yi2 = fmaf(a1, ks[1][2], fmaf(a0, ks[0][2], y2));
            feval(fmaf((float)(3.0/10.0), dt_c, t), yi0, yi1, yi2, ks[2]); }
        {   const float a0 = dt_c*(float)(44.0/45.0), a1 = dt_c*(float)(-56.0/15.0),
                        a2 = dt_c*(float)(32.0/9.0);
            float yi0 = fmaf(a2, ks[2][0], fmaf(a1, ks[1][0], fmaf(a0, ks[0][0], y0)));
            float yi1 = fmaf(a2, ks[2][1], fmaf(a1, ks[1][1], fmaf(a0, ks[0][1], y1)));
            float yi2 = fmaf(a2, ks[2][2], fmaf(a1, ks[1][2], fmaf(a0, ks[0][2], y2)));
            feval(fmaf((float)(4.0/5.0), dt_c, t), yi0, yi1, yi2, ks[3]); }
        {   const float a0 = dt_c*(float)(19372.0/6561.0), a1 = dt_c*(float)(-25360.0/2187.0),
                        a2 = dt_c*(float)(64448.0/6561.0), a3 = dt_c*(float)(-212.0/729.0);
            float yi0 = fmaf(a3, ks[3][0], fmaf(a2, ks[2][0], fmaf(a1, ks[1][0], fmaf(a0, ks[0][0], y0))));
            float yi1 = fmaf(a3, ks[3][1], fmaf(a2, ks[2][1], fmaf(a1, ks[1][1], fmaf(a0, ks[0][1], y1))));
            float yi2 = fmaf(a3, ks[3][2], fmaf(a2, ks[2][2], fmaf(a1, ks[1][2], fmaf(a0, ks[0][2], y2))));
            feval(fmaf((float)(8.0/9.0), dt_c, t), yi0, yi1, yi2, ks[4]); }
        {   const float a0 = dt_c*(float)(9017.0/3168.0), a1 = dt_c*(float)(-355.0/33.0),
                        a2 = dt_c*(float)(46732.0/5247.0), a3 = dt_c*(float)(49.0/176.0),
                        a4 = dt_c*(float)(-5103.0/18656.0);
            float yi0 = fmaf(a4, ks[4][0], fmaf(a3, ks[3][0], fmaf(a2, ks[2][0], fmaf(a1, ks[1][0], fmaf(a0, ks[0][0], y0)))));
            float yi1 = fmaf(a4, ks[4][1], fmaf(a3, ks[3][1], fmaf(a2, ks[2][1], fmaf(a1, ks[1][1], fmaf(a0, ks[0][1], y1)))));
            float yi2 = fmaf(a4, ks[4][2], fmaf(a3, ks[3][2], fmaf(a2, ks[2][2], fmaf(a1, ks[1][2], fmaf(a0, ks[0][2], y2)))));
            feval(t + dt_c, yi0, yi1, yi2, ks[5]); }
        {   const float a0 = dt_c*(float)(35.0/384.0), a2 = dt_c*(float)(500.0/1113.0),
                        a3 = dt_c*(float)(125.0/192.0), a4 = dt_c*(float)(-2187.0/6784.0),
                        a5 = dt_c*(float)(11.0/84.0);
            float yi0 = fmaf(a5, ks[5][0], fmaf(a4, ks[4][0], fmaf(a3, ks[3][0], fmaf(a2, ks[2][0], fmaf(a0, ks[0][0], y0)))));
            float yi1 = fmaf(a5, ks[5][1], fmaf(a4, ks[4][1], fmaf(a3, ks[3][1], fmaf(a2, ks[2][1], fmaf(a0, ks[0][1], y1)))));
            float yi2 = fmaf(a5, ks[5][2], fmaf(a4, ks[4][2], fmaf(a3, ks[3][2], fmaf(a2, ks[2][2], fmaf(a0, ks[0][2], y2)))));
            feval(t + dt_c, yi0, yi1, yi2, ks[6]); }

        // ---- 5th-order solution + embedded error ----
        const float db0 = dt_c*(float)(35.0/384.0), db2 = dt_c*(float)(500.0/1113.0),
                    db3 = dt_c*(float)(125.0/192.0), db4 = dt_c*(float)(-2187.0/6784.0),
                    db5 = dt_c*(float)(11.0/84.0);
        float y5_0 = fmaf(db5, ks[5][0], fmaf(db4, ks[4][0], fmaf(db3, ks[3][0], fmaf(db2, ks[2][0], fmaf(db0, ks[0][0], y0)))));
        float y5_1 = fmaf(db5, ks[5][1], fmaf(db4, ks[4][1], fmaf(db3, ks[3][1], fmaf(db2, ks[2][1], fmaf(db0, ks[0][1], y1)))));
        float y5_2 = fmaf(db5, ks[5][2], fmaf(db4, ks[4][2], fmaf(db3, ks[3][2], fmaf(db2, ks[2][2], fmaf(db0, ks[0][2], y2)))));

        const float de0 = dt_c*(float)(35.0/384.0   - 5179.0/57600.0);
        const float de2 = dt_c*(float)(500.0/1113.0 - 7571.0/16695.0);
        const float de3 = dt_c*(float)(125.0/192.0  - 393.0/640.0);
        const float de4 = dt_c*(float)(-2187.0/6784.0 + 92097.0/339200.0);
        const float de5 = dt_c*(float)(11.0/84.0    - 187.0/2100.0);
        const float de6 = dt_c*(float)(-1.0/40.0);
        float e_0 = fmaf(de6, ks[6][0], fmaf(de5, ks[5][0], fmaf(de4, ks[4][0], fmaf(de3, ks[3][0], fmaf(de2, ks[2][0], de0*ks[0][0])))));
        float e_1 = fmaf(de6, ks[6][1], fmaf(de5, ks[5][1], fmaf(de4, ks[4][1], fmaf(de3, ks[3][1], fmaf(de2, ks[2][1], de0*ks[0][1])))));
        float e_2 = fmaf(de6, ks[6][2], fmaf(de5, ks[5][2], fmaf(de4, ks[4][2], fmaf(de3, ks[3][2], fmaf(de2, ks[2][2], de0*ks[0][2])))));

        float e2 = 0.f;
        {   float tol = fmaf(1e-5f, fmaxf(fabsf(y0), fabsf(y5_0)), 1e-5f); float r = e_0/tol; e2 = fmaf(r,r,e2); }
        {   float tol = fmaf(1e-5f, fmaxf(fabsf(y1), fabsf(y5_1)), 1e-5f); float r = e_1/tol; e2 = fmaf(r,r,e2); }
        {   float tol = fmaf(1e-5f, fmaxf(fabsf(y2), fabsf(y5_2)), 1e-5f); float r = e_2/tol; e2 = fmaf(r,r,e2); }

        // ---- deterministic global error norm ----
        if (slice == 0) red[p] = e2;
        __syncthreads();
        if (tid == 0) {
            float s = 0.f;
            for (int q = 0; q < PPB; ++q) s += red[q];
            __hip_atomic_store(&part[(step & 1)*NBLK + (int)blockIdx.x], s,
                               __ATOMIC_RELEASE, __HIP_MEMORY_SCOPE_AGENT);
        }
        grid.sync();
        float* pb = part + (step & 1)*NBLK;
        float t0s = 0.f, t1s = 0.f, t2s = 0.f, t3s = 0.f;
        for (int q = 0; q < NBLK; q += 4) {
            t0s += __hip_atomic_load(&pb[q+0], __ATOMIC_ACQUIRE, __HIP_MEMORY_SCOPE_AGENT);
            t1s += __hip_atomic_load(&pb[q+1], __ATOMIC_ACQUIRE, __HIP_MEMORY_SCOPE_AGENT);
            t2s += __hip_atomic_load(&pb[q+2], __ATOMIC_ACQUIRE, __HIP_MEMORY_SCOPE_AGENT);
            t3s += __hip_atomic_load(&pb[q+3], __ATOMIC_ACQUIRE, __HIP_MEMORY_SCOPE_AGENT);
        }
        const float tot = (t0s + t1s) + (t2s + t3s);
        float err = sqrtf(tot / (float)(NPTS * 3));
        err = fmaxf(err, 1e-10f);
        const bool accept = (err <= 1.0f);
        const float factor = fminf(fmaxf(0.9f * __powf(err, -0.2f), 0.2f), 10.0f);
        if (accept) { t = t + dt_c; y0 = y5_0; y1 = y5_1; y2 = y5_2; }
        dt = dt_c * factor;
    }

    // protect partial-buffer (may alias yout) from early overwrites
    grid.sync();
    if (slice == 0) {
        yout[3*gp+0] = y0;
        yout[3*gp+1] = y1;
        yout[3*gp+2] = y2;
    }
}

extern "C" void kernel_launch(void* const* d_in, const int* in_sizes, int n_in,
                              void* d_out, int out_size, void* d_ws, size_t ws_size,
                              hipStream_t stream) {
    const float* y  = (const float*)d_in[0];
    const float* W1 = (const float*)d_in[1];
    const float* b1 = (const float*)d_in[2];
    const float* W2 = (const float*)d_in[3];
    const float* b2 = (const float*)d_in[4];
    const float* W3 = (const float*)d_in[5];
    const float* b3 = (const float*)d_in[6];
    float* out  = (float*)d_out;
    float* part = (ws_size >= (size_t)(2*NBLK*sizeof(float))) ? (float*)d_ws : (float*)d_out;

    void* args[] = { (void*)&y, (void*)&W1, (void*)&b1, (void*)&W2, (void*)&b2,
                     (void*)&W3, (void*)&b3, (void*)&out, (void*)&part };
    hipLaunchCooperativeKernel((const void*)ode_dopri5, dim3(NBLK), dim3(256),
                               args, 0, stream);
}

// Round 2
// 259.155 us; speedup vs baseline: 87.5096x; 87.5096x over previous
//
#include <hip/hip_runtime.h>

#define NPTS   32768
#define NBLK   512
#define PPB    64     // points per block
#define SL     16     // hidden-slice per thread (4 slices x 16 = H)
#define HDIM   64
#define MAXSTEPS 24
#define N3     (NPTS*3)

// ws float layout:
//   [0 .. 512)            per-block error partials
//   [512 .. 1024)         flags: slot k at 512+4k = {t, dt, accept, active}
//   [1024 .. 1024+N3)     Y0 (committed y)
//   [1024+N3 .. 1024+2N3) Y1 (proposal)   -- falls back to d_out if ws too small

__device__ __forceinline__ float fast_tanh(float x) {
    float e = __expf(2.0f * x);
    return fmaf(-2.0f, __builtin_amdgcn_rcpf(1.0f + e), 1.0f);
}

__global__ void __launch_bounds__(256)
step_kernel(int step,
            const float* __restrict__ yin,
            const float* __restrict__ W1, const float* __restrict__ b1,
            const float* __restrict__ W2, const float* __restrict__ b2,
            const float* __restrict__ W3, const float* __restrict__ b3,
            float* __restrict__ Y0, float* __restrict__ Y1,
            float* __restrict__ part, const float* __restrict__ flags)
{
    __shared__ float h1s[PPB * 65];   // stride 65: conflict-free
    __shared__ float outp[PPB * 13];
    __shared__ float red[PPB];

    const int tid   = threadIdx.x;
    const int p     = tid & 63;
    const int slice = __builtin_amdgcn_readfirstlane((int)(tid >> 6));
    const int s16   = slice * SL;
    const int p65   = p * 65;
    const int p13   = p * 13;
    const int gp    = (int)blockIdx.x * PPB + p;

    float t, dt; bool accPrev, active;
    if (step == 0) { t = 0.0f; dt = 0.05f; accPrev = false; active = true; }
    else {
        const float* fl = flags + 4*step;
        t = fl[0]; dt = fl[1]; accPrev = (fl[2] != 0.0f); active = (fl[3] != 0.0f);
    }

    if (!active) {                       // no-op step: just commit pending accept
        if (accPrev && slice == 0) {
            Y0[3*gp+0] = Y1[3*gp+0];
            Y0[3*gp+1] = Y1[3*gp+1];
            Y0[3*gp+2] = Y1[3*gp+2];
        }
        return;                          // uniform branch: no barrier divergence
    }

    float y0, y1, y2;
    if (step == 0)      { y0 = yin[3*gp+0]; y1 = yin[3*gp+1]; y2 = yin[3*gp+2]; }
    else if (accPrev)   { y0 = Y1[3*gp+0];  y1 = Y1[3*gp+1];  y2 = Y1[3*gp+2];  }
    else                { y0 = Y0[3*gp+0];  y1 = Y0[3*gp+1];  y2 = Y0[3*gp+2];  }

    const float dt_c = fminf(dt, 1.0f - t);
    float ks[7][3];

    auto feval = [&](float ts, float yi0, float yi1, float yi2, float* kout) {
        float h1v[SL];
        #pragma unroll
        for (int kk = 0; kk < SL; ++kk) {
            const int k = s16 + kk;
            float a = b1[k];
            a = fmaf(yi0, W1[k],        a);
            a = fmaf(yi1, W1[HDIM+k],   a);
            a = fmaf(yi2, W1[2*HDIM+k], a);
            a = fmaf(ts,  W1[3*HDIM+k], a);
            h1v[kk] = fast_tanh(a);
        }
        #pragma unroll
        for (int kk = 0; kk < SL; ++kk) h1s[p65 + s16 + kk] = h1v[kk];
        __syncthreads();
        float acc[SL];
        #pragma unroll
        for (int kk = 0; kk < SL; ++kk) acc[kk] = b2[s16 + kk];
        #pragma unroll 4
        for (int j = 0; j < HDIM; ++j) {
            const float hj = h1s[p65 + j];
            const float* __restrict__ w = W2 + j*HDIM + s16;   // wave-uniform -> s_load
            #pragma unroll
            for (int kk = 0; kk < SL; ++kk) acc[kk] = fmaf(w[kk], hj, acc[kk]);
        }
        float po0 = 0.f, po1 = 0.f, po2 = 0.f;
        #pragma unroll
        for (int kk = 0; kk < SL; ++kk) {
            const float h2 = fast_tanh(acc[kk]);
            const float* __restrict__ w3 = W3 + 3*(s16+kk);
            po0 = fmaf(h2, w3[0], po0);
            po1 = fmaf(h2, w3[1], po1);
            po2 = fmaf(h2, w3[2], po2);
        }
        outp[p13 + 3*slice + 0] = po0;
        outp[p13 + 3*slice + 1] = po1;
        outp[p13 + 3*slice + 2] = po2;
        __syncthreads();
        float c0 = b3[0], c1 = b3[1], c2 = b3[2];
        #pragma unroll
        for (int s2 = 0; s2 < 4; ++s2) {
            c0 += outp[p13 + 3*s2 + 0];
            c1 += outp[p13 + 3*s2 + 1];
            c2 += outp[p13 + 3*s2 + 2];
        }
        kout[0] = c0; kout[1] = c1; kout[2] = c2;
    };

    feval(t, y0, y1, y2, ks[0]);
    {   const float a = dt_c * (float)(1.0/5.0);
        feval(fmaf((float)(1.0/5.0), dt_c, t),
              fmaf(a, ks[0][0], y0), fmaf(a, ks[0][1], y1), fmaf(a, ks[0][2], y2), ks[1]); }
    {   const float a0 = dt_c*(float)(3.0/40.0), a1 = dt_c*(float)(9.0/40.0);
        float yi0 = fmaf(a1, ks[1][0], fmaf(a0, ks[0][0], y0));
        float yi1 = fmaf(a1, ks[1][1], fmaf(a0, ks[0][1], y1));
        float yi2 = fmaf(a1, ks[1][2], fmaf(a0, ks[0][2], y2));
        feval(fmaf((float)(3.0/10.0), dt_c, t), yi0, yi1, yi2, ks[2]); }
    {   const float a0 = dt_c*(float)(44.0/45.0), a1 = dt_c*(float)(-56.0/15.0),
                    a2 = dt_c*(float)(32.0/9.0);
        float yi0 = fmaf(a2, ks[2][0], fmaf(a1, ks[1][0], fmaf(a0, ks[0][0], y0)));
        float yi1 = fmaf(a2, ks[2][1], fmaf(a1, ks[1][1], fmaf(a0, ks[0][1], y1)));
        float yi2 = fmaf(a2, ks[2][2], fmaf(a1, ks[1][2], fmaf(a0, ks[0][2], y2)));
        feval(fmaf((float)(4.0/5.0), dt_c, t), yi0, yi1, yi2, ks[3]); }
    {   const float a0 = dt_c*(float)(19372.0/6561.0), a1 = dt_c*(float)(-25360.0/2187.0),
                    a2 = dt_c*(float)(64448.0/6561.0), a3 = dt_c*(float)(-212.0/729.0);
        float yi0 = fmaf(a3, ks[3][0], fmaf(a2, ks[2][0], fmaf(a1, ks[1][0], fmaf(a0, ks[0][0], y0))));
        float yi1 = fmaf(a3, ks[3][1], fmaf(a2, ks[2][1], fmaf(a1, ks[1][1], fmaf(a0, ks[0][1], y1))));
        float yi2 = fmaf(a3, ks[3][2], fmaf(a2, ks[2][2], fmaf(a1, ks[1][2], fmaf(a0, ks[0][2], y2))));
        feval(fmaf((float)(8.0/9.0), dt_c, t), yi0, yi1, yi2, ks[4]); }
    {   const float a0 = dt_c*(float)(9017.0/3168.0), a1 = dt_c*(float)(-355.0/33.0),
                    a2 = dt_c*(float)(46732.0/5247.0), a3 = dt_c*(float)(49.0/176.0),
                    a4 = dt_c*(float)(-5103.0/18656.0);
        float yi0 = fmaf(a4, ks[4][0], fmaf(a3, ks[3][0], fmaf(a2, ks[2][0], fmaf(a1, ks[1][0], fmaf(a0, ks[0][0], y0)))));
        float yi1 = fmaf(a4, ks[4][1], fmaf(a3, ks[3][1], fmaf(a2, ks[2][1], fmaf(a1, ks[1][1], fmaf(a0, ks[0][1], y1)))));
        float yi2 = fmaf(a4, ks[4][2], fmaf(a3, ks[3][2], fmaf(a2, ks[2][2], fmaf(a1, ks[1][2], fmaf(a0, ks[0][2], y2)))));
        feval(t + dt_c, yi0, yi1, yi2, ks[5]); }
    {   const float a0 = dt_c*(float)(35.0/384.0), a2 = dt_c*(float)(500.0/1113.0),
                    a3 = dt_c*(float)(125.0/192.0), a4 = dt_c*(float)(-2187.0/6784.0),
                    a5 = dt_c*(float)(11.0/84.0);
        float yi0 = fmaf(a5, ks[5][0], fmaf(a4, ks[4][0], fmaf(a3, ks[3][0], fmaf(a2, ks[2][0], fmaf(a0, ks[0][0], y0)))));
        float yi1 = fmaf(a5, ks[5][1], fmaf(a4, ks[4][1], fmaf(a3, ks[3][1], fmaf(a2, ks[2][1], fmaf(a0, ks[0][1], y1)))));
        float yi2 = fmaf(a5, ks[5][2], fmaf(a4, ks[4][2], fmaf(a3, ks[3][2], fmaf(a2, ks[2][2], fmaf(a0, ks[0][2], y2)))));
        feval(t + dt_c, yi0, yi1, yi2, ks[6]); }

    const float db0 = dt_c*(float)(35.0/384.0), db2 = dt_c*(float)(500.0/1113.0),
                db3 = dt_c*(float)(125.0/192.0), db4 = dt_c*(float)(-2187.0/6784.0),
                db5 = dt_c*(float)(11.0/84.0);
    float y5_0 = fmaf(db5, ks[5][0], fmaf(db4, ks[4][0], fmaf(db3, ks[3][0], fmaf(db2, ks[2][0], fmaf(db0, ks[0][0], y0)))));
    float y5_1 = fmaf(db5, ks[5][1], fmaf(db4, ks[4][1], fmaf(db3, ks[3][1], fmaf(db2, ks[2][1], fmaf(db0, ks[0][1], y1)))));
    float y5_2 = fmaf(db5, ks[5][2], fmaf(db4, ks[4][2], fmaf(db3, ks[3][2], fmaf(db2, ks[2][2], fmaf(db0, ks[0][2], y2)))));

    const float de0 = dt_c*(float)(35.0/384.0   - 5179.0/57600.0);
    const float de2 = dt_c*(float)(500.0/1113.0 - 7571.0/16695.0);
    const float de3 = dt_c*(float)(125.0/192.0  - 393.0/640.0);
    const float de4 = dt_c*(float)(-2187.0/6784.0 + 92097.0/339200.0);
    const float de5 = dt_c*(float)(11.0/84.0    - 187.0/2100.0);
    const float de6 = dt_c*(float)(-1.0/40.0);
    float e_0 = fmaf(de6, ks[6][0], fmaf(de5, ks[5][0], fmaf(de4, ks[4][0], fmaf(de3, ks[3][0], fmaf(de2, ks[2][0], de0*ks[0][0])))));
    float e_1 = fmaf(de6, ks[6][1], fmaf(de5, ks[5][1], fmaf(de4, ks[4][1], fmaf(de3, ks[3][1], fmaf(de2, ks[2][1], de0*ks[0][1])))));
    float e_2 = fmaf(de6, ks[6][2], fmaf(de5, ks[5][2], fmaf(de4, ks[4][2], fmaf(de3, ks[3][2], fmaf(de2, ks[2][2], de0*ks[0][2])))));

    float e2 = 0.f;
    {   float tol = fmaf(1e-5f, fmaxf(fabsf(y0), fabsf(y5_0)), 1e-5f); float r = e_0/tol; e2 = fmaf(r,r,e2); }
    {   float tol = fmaf(1e-5f, fmaxf(fabsf(y1), fabsf(y5_1)), 1e-5f); float r = e_1/tol; e2 = fmaf(r,r,e2); }
    {   float tol = fmaf(1e-5f, fmaxf(fabsf(y2), fabsf(y5_2)), 1e-5f); float r = e_2/tol; e2 = fmaf(r,r,e2); }

    // commit current y and publish proposal (after all barriers -> no read races)
    if (slice == 0) {
        Y0[3*gp+0] = y0;   Y0[3*gp+1] = y1;   Y0[3*gp+2] = y2;
        Y1[3*gp+0] = y5_0; Y1[3*gp+1] = y5_1; Y1[3*gp+2] = y5_2;
        red[p] = e2;
    }
    __syncthreads();
    if (tid == 0) {
        float s = 0.f;
        for (int q = 0; q < PPB; ++q) s += red[q];   // fixed order, deterministic
        part[blockIdx.x] = s;
    }
}

__global__ void __launch_bounds__(256)
ctrl_kernel(int step, const float* __restrict__ part, float* __restrict__ flags)
{
    __shared__ float s[256];
    const int tid = threadIdx.x;
    float t, dt; bool active;
    if (step == 0) { t = 0.0f; dt = 0.05f; active = true; }
    else {
        const float* fl = flags + 4*step;
        t = fl[0]; dt = fl[1]; active = (fl[3] != 0.0f);
    }
    float* out = flags + 4*(step+1);
    if (!active) {
        if (tid == 0) { out[0] = t; out[1] = dt; out[2] = 0.0f; out[3] = 0.0f; }
        return;
    }
    s[tid] = part[tid] + part[tid + 256];
    __syncthreads();
    for (int off = 128; off > 0; off >>= 1) {        // fixed tree, deterministic
        if (tid < off) s[tid] += s[tid + off];
        __syncthreads();
    }
    if (tid == 0) {
        const float dt_c = fminf(dt, 1.0f - t);
        float err = sqrtf(s[0] / (float)(NPTS * 3));
        err = fmaxf(err, 1e-10f);
        const bool accept = (err <= 1.0f);
        const float factor = fminf(fmaxf(0.9f * __powf(err, -0.2f), 0.2f), 10.0f);
        const float tn  = accept ? (t + dt_c) : t;
        const float dtn = dt_c * factor;
        const bool actn = (1.0f - tn) > 1e-9f;
        out[0] = tn; out[1] = dtn;
        out[2] = accept ? 1.0f : 0.0f;
        out[3] = actn  ? 1.0f : 0.0f;
    }
}

__global__ void __launch_bounds__(256)
final_kernel(const float* __restrict__ flags,
             const float* __restrict__ Y0, const float* __restrict__ Y1,
             float* __restrict__ out)
{
    const int i = (int)blockIdx.x * 256 + (int)threadIdx.x;
    if (i < N3) {
        const bool acc = (flags[4*MAXSTEPS + 2] != 0.0f);
        out[i] = acc ? Y1[i] : Y0[i];
    }
}

extern "C" void kernel_launch(void* const* d_in, const int* in_sizes, int n_in,
                              void* d_out, int out_size, void* d_ws, size_t ws_size,
                              hipStream_t stream) {
    const float* y  = (const float*)d_in[0];
    const float* W1 = (const float*)d_in[1];
    const float* b1 = (const float*)d_in[2];
    const float* W2 = (const float*)d_in[3];
    const float* b2 = (const float*)d_in[4];
    const float* W3 = (const float*)d_in[5];
    const float* b3 = (const float*)d_in[6];

    float* ws    = (float*)d_ws;
    float* part  = ws;
    float* flags = ws + 512;
    float* Y0    = ws + 1024;
    float* Y1;
    const size_t need_full = (size_t)(1024 + 2*(size_t)N3) * sizeof(float);
    if (ws_size >= need_full) Y1 = Y0 + N3;
    else                      Y1 = (float*)d_out;   // output buffer doubles as proposal

    for (int s = 0; s < MAXSTEPS; ++s) {
        step_kernel<<<dim3(NBLK), dim3(256), 0, stream>>>(
            s, y, W1, b1, W2, b2, W3, b3, Y0, Y1, part, flags);
        ctrl_kernel<<<dim3(1), dim3(256), 0, stream>>>(s, part, flags);
    }
    final_kernel<<<dim3((N3 + 255) / 256), dim3(256), 0, stream>>>(
        flags, Y0, Y1, (float*)d_out);
}

// Round 3
// 228.843 us; speedup vs baseline: 99.1011x; 1.1325x over previous
//
#include <hip/hip_runtime.h>

#define NPTS 32768
#define NBLK 512
#define HDIM 64
#define MAXSTEPS 24
#define N3 (NPTS*3)

typedef __attribute__((ext_vector_type(8))) short short8;
typedef __attribute__((ext_vector_type(4))) float f32x4;

union U8 { uint4 v; short8 s; };

__device__ __forceinline__ float fast_tanh(float x) {
    float e = __expf(2.0f * x);
    return fmaf(-2.0f, __builtin_amdgcn_rcpf(1.0f + e), 1.0f);
}

__device__ __forceinline__ uint32_t bf16_rne(float x) {
    uint32_t u = __float_as_uint(x);
    return (u + 0x7FFFu + ((u >> 16) & 1u)) >> 16;
}

// split (x0,x1) into packed hi-bf16 pair (truncation) and lo-bf16 pair (RNE of residual)
__device__ __forceinline__ void split_pair(float x0, float x1, uint32_t& hw, uint32_t& lw) {
    uint32_t u0 = __float_as_uint(x0), u1 = __float_as_uint(x1);
    uint32_t h0 = u0 & 0xFFFF0000u,  h1 = u1 & 0xFFFF0000u;
    float l0 = x0 - __uint_as_float(h0);    // exact
    float l1 = x1 - __uint_as_float(h1);    // exact
    hw = (u0 >> 16) | h1;
    lw = bf16_rne(l0) | (bf16_rne(l1) << 16);
}

__global__ void __launch_bounds__(256, 2)
step_kernel(int step,
            const float* __restrict__ yin,
            const float* __restrict__ W1, const float* __restrict__ b1,
            const float* __restrict__ W2, const float* __restrict__ b2,
            const float* __restrict__ W3, const float* __restrict__ b3,
            float* __restrict__ Y0, float* __restrict__ Y1,
            float* __restrict__ part, float* __restrict__ flags,
            int* __restrict__ cnt)
{
    // H1 planes: row=point (64), 64 bf16 cols packed in 32 dwords, stride 36 dwords
    // (stride%32==4 -> uniform 8-accesses/bank for b128 ops; %4==0 -> 16B aligned)
    __shared__ uint32_t H1hi[64*36];
    __shared__ uint32_t H1lo[64*36];
    __shared__ float    kbuf[64*5];    // stride 5: conflict-free b32
    __shared__ float    cs[256];
    __shared__ int      islast_s;

    const int tid = threadIdx.x;
    const int p   = tid & 63;                 // state point (replicated across 4 waves)
    const int l15 = tid & 15;
    const int q   = (tid >> 4) & 3;
    const int wu  = __builtin_amdgcn_readfirstlane((int)(threadIdx.x >> 6));
    const int gp  = (int)blockIdx.x * 64 + p;

    float t, dt; bool accPrev, active;
    if (step == 0) { t = 0.f; dt = 0.05f; accPrev = false; active = true; }
    else {
        const float* fl = flags + 4*step;
        t = fl[0]; dt = fl[1]; accPrev = (fl[2] != 0.f); active = (fl[3] != 0.f);
    }

    if (!active) {                 // no-op step: just commit pending accept
        if (accPrev && tid < 64) {
            Y0[3*gp+0] = Y1[3*gp+0]; Y0[3*gp+1] = Y1[3*gp+1]; Y0[3*gp+2] = Y1[3*gp+2];
        }
        return;
    }

    float y0, y1, y2;
    if (step == 0)    { y0 = yin[3*gp]; y1 = yin[3*gp+1]; y2 = yin[3*gp+2]; }
    else if (accPrev) { y0 = Y1[3*gp];  y1 = Y1[3*gp+1];  y2 = Y1[3*gp+2];  }
    else              { y0 = Y0[3*gp];  y1 = Y0[3*gp+1];  y2 = Y0[3*gp+2];  }

    const float dt_c = fminf(dt, 1.0f - t);

    // ---- static per-lane preloads (once per kernel) ----
    // A-frags: W2^T[m=16a+l15][k=32h+8q+j]  (hi/lo split)
    short8 w2h[4][2], w2l[4][2];
    #pragma unroll
    for (int a = 0; a < 4; a++)
    #pragma unroll
    for (int h = 0; h < 2; h++) {
        uint32_t hw[4], lw[4];
        #pragma unroll
        for (int j2 = 0; j2 < 4; j2++) {
            const int k0 = 32*h + 8*q + 2*j2;
            float x0 = W2[(k0    )*64 + 16*a + l15];
            float x1 = W2[(k0 + 1)*64 + 16*a + l15];
            split_pair(x0, x1, hw[j2], lw[j2]);
        }
        U8 uh; uh.v = make_uint4(hw[0], hw[1], hw[2], hw[3]); w2h[a][h] = uh.s;
        U8 ul; ul.v = make_uint4(lw[0], lw[1], lw[2], lw[3]); w2l[a][h] = ul.s;
    }
    float b2v[4][4], w3v[4][4][3];
    #pragma unroll
    for (int a = 0; a < 4; a++)
    #pragma unroll
    for (int r = 0; r < 4; r++) {
        const int n = 16*a + 4*q + r;
        b2v[a][r] = b2[n];
        w3v[a][r][0] = W3[n*3+0]; w3v[a][r][1] = W3[n*3+1]; w3v[a][r][2] = W3[n*3+2];
    }
    const float b30 = b3[0], b31 = b3[1], b32s = b3[2];

    float ks[7][3];

    auto feval = [&](float ts, float yi0, float yi1, float yi2, float* kout) {
        // ---- layer 1 (producer): point p, cols [16wu, 16wu+16)  (W1 wave-uniform -> s_load)
        uint32_t hiw[8], low[8];
        #pragma unroll
        for (int c2 = 0; c2 < 8; c2++) {
            const int k0 = 16*wu + 2*c2;
            float pre0 = b1[k0];
            pre0 = fmaf(yi0, W1[k0],       pre0);
            pre0 = fmaf(yi1, W1[64 + k0],  pre0);
            pre0 = fmaf(yi2, W1[128 + k0], pre0);
            pre0 = fmaf(ts , W1[192 + k0], pre0);
            float pre1 = b1[k0+1];
            pre1 = fmaf(yi0, W1[k0+1],       pre1);
            pre1 = fmaf(yi1, W1[64 + k0+1],  pre1);
            pre1 = fmaf(yi2, W1[128 + k0+1], pre1);
            pre1 = fmaf(ts , W1[192 + k0+1], pre1);
            split_pair(fast_tanh(pre0), fast_tanh(pre1), hiw[c2], low[c2]);
        }
        {
            uint32_t* dh = H1hi + p*36 + 8*wu;
            *(uint4*)(dh)     = make_uint4(hiw[0], hiw[1], hiw[2], hiw[3]);
            *(uint4*)(dh + 4) = make_uint4(hiw[4], hiw[5], hiw[6], hiw[7]);
            uint32_t* dl = H1lo + p*36 + 8*wu;
            *(uint4*)(dl)     = make_uint4(low[0], low[1], low[2], low[3]);
            *(uint4*)(dl + 4) = make_uint4(low[4], low[5], low[6], low[7]);
        }
        __syncthreads();   // H1 ready (also: all kbuf reads of prev stage done)

        // ---- layer 2 (MFMA): H2^T = W2^T @ H1^T, B-frag = H1[16wu+l15][k]
        const uint32_t* rhi = H1hi + (16*wu + l15)*36 + 4*q;
        const uint32_t* rlo = H1lo + (16*wu + l15)*36 + 4*q;
        U8 bh0, bh1, bl0, bl1;
        bh0.v = *(const uint4*)(rhi);
        bh1.v = *(const uint4*)(rhi + 16);
        bl0.v = *(const uint4*)(rlo);
        bl1.v = *(const uint4*)(rlo + 16);
        f32x4 acc[4];
        #pragma unroll
        for (int a = 0; a < 4; a++) acc[a] = (f32x4)(0.0f);
        #pragma unroll
        for (int a = 0; a < 4; a++) {
            acc[a] = __builtin_amdgcn_mfma_f32_16x16x32_bf16(w2h[a][0], bh0.s, acc[a], 0, 0, 0);
            acc[a] = __builtin_amdgcn_mfma_f32_16x16x32_bf16(w2h[a][1], bh1.s, acc[a], 0, 0, 0);
            acc[a] = __builtin_amdgcn_mfma_f32_16x16x32_bf16(w2h[a][0], bl0.s, acc[a], 0, 0, 0);
            acc[a] = __builtin_amdgcn_mfma_f32_16x16x32_bf16(w2h[a][1], bl1.s, acc[a], 0, 0, 0);
            acc[a] = __builtin_amdgcn_mfma_f32_16x16x32_bf16(w2l[a][0], bh0.s, acc[a], 0, 0, 0);
            acc[a] = __builtin_amdgcn_mfma_f32_16x16x32_bf16(w2l[a][1], bh1.s, acc[a], 0, 0, 0);
        }
        // ---- layer 3: lane holds h2 of 16 neurons for its OWN point (16wu+l15)
        float po0 = 0.f, po1 = 0.f, po2 = 0.f;
        #pragma unroll
        for (int a = 0; a < 4; a++)
        #pragma unroll
        for (int r = 0; r < 4; r++) {
            float h2 = fast_tanh(acc[a][r] + b2v[a][r]);
            po0 = fmaf(h2, w3v[a][r][0], po0);
            po1 = fmaf(h2, w3v[a][r][1], po1);
            po2 = fmaf(h2, w3v[a][r][2], po2);
        }
        po0 += __shfl_xor(po0, 16); po0 += __shfl_xor(po0, 32);
        po1 += __shfl_xor(po1, 16); po1 += __shfl_xor(po1, 32);
        po2 += __shfl_xor(po2, 16); po2 += __shfl_xor(po2, 32);
        if ((tid & 63) < 16) {                  // quad 0 publishes k for point 16wu+l15
            float* kb = kbuf + (16*wu + l15)*5;
            kb[0] = po0 + b30; kb[1] = po1 + b31; kb[2] = po2 + b32s;
        }
        __syncthreads();   // kbuf ready
        const float* kr = kbuf + p*5;
        kout[0] = kr[0]; kout[1] = kr[1]; kout[2] = kr[2];
    };

    // ---- 7 dopri5 stages ----
    feval(t, y0, y1, y2, ks[0]);
    {   const float a = dt_c * (float)(1.0/5.0);
        feval(fmaf((float)(1.0/5.0), dt_c, t),
              fmaf(a, ks[0][0], y0), fmaf(a, ks[0][1], y1), fmaf(a, ks[0][2], y2), ks[1]); }
    {   const float a0 = dt_c*(float)(3.0/40.0), a1 = dt_c*(float)(9.0/40.0);
        float yi0 = fmaf(a1, ks[1][0], fmaf(a0, ks[0][0], y0));
        float yi1 = fmaf(a1, ks[1][1], fmaf(a0, ks[0][1], y1));
        float yi2 = fmaf(a1, ks[1][2], fmaf(a0, ks[0][2], y2));
        feval(fmaf((float)(3.0/10.0), dt_c, t), yi0, yi1, yi2, ks[2]); }
    {   const float a0 = dt_c*(float)(44.0/45.0), a1 = dt_c*(float)(-56.0/15.0),
                    a2 = dt_c*(float)(32.0/9.0);
        float yi0 = fmaf(a2, ks[2][0], fmaf(a1, ks[1][0], fmaf(a0, ks[0][0], y0)));
        float yi1 = fmaf(a2, ks[2][1], fmaf(a1, ks[1][1], fmaf(a0, ks[0][1], y1)));
        float yi2 = fmaf(a2, ks[2][2], fmaf(a1, ks[1][2], fmaf(a0, ks[0][2], y2)));
        feval(fmaf((float)(4.0/5.0), dt_c, t), yi0, yi1, yi2, ks[3]); }
    {   const float a0 = dt_c*(float)(19372.0/6561.0), a1 = dt_c*(float)(-25360.0/2187.0),
                    a2 = dt_c*(float)(64448.0/6561.0), a3 = dt_c*(float)(-212.0/729.0);
        float yi0 = fmaf(a3, ks[3][0], fmaf(a2, ks[2][0], fmaf(a1, ks[1][0], fmaf(a0, ks[0][0], y0))));
        float yi1 = fmaf(a3, ks[3][1], fmaf(a2, ks[2][1], fmaf(a1, ks[1][1], fmaf(a0, ks[0][1], y1))));
        float yi2 = fmaf(a3, ks[3][2], fmaf(a2, ks[2][2], fmaf(a1, ks[1][2], fmaf(a0, ks[0][2], y2))));
        feval(fmaf((float)(8.0/9.0), dt_c, t), yi0, yi1, yi2, ks[4]); }
    {   const float a0 = dt_c*(float)(9017.0/3168.0), a1 = dt_c*(float)(-355.0/33.0),
                    a2 = dt_c*(float)(46732.0/5247.0), a3 = dt_c*(float)(49.0/176.0),
                    a4 = dt_c*(float)(-5103.0/18656.0);
        float yi0 = fmaf(a4, ks[4][0], fmaf(a3, ks[3][0], fmaf(a2, ks[2][0], fmaf(a1, ks[1][0], fmaf(a0, ks[0][0], y0)))));
        float yi1 = fmaf(a4, ks[4][1], fmaf(a3, ks[3][1], fmaf(a2, ks[2][1], fmaf(a1, ks[1][1], fmaf(a0, ks[0][1], y1)))));
        float yi2 = fmaf(a4, ks[4][2], fmaf(a3, ks[3][2], fmaf(a2, ks[2][2], fmaf(a1, ks[1][2], fmaf(a0, ks[0][2], y2)))));
        feval(t + dt_c, yi0, yi1, yi2, ks[5]); }
    {   const float a0 = dt_c*(float)(35.0/384.0), a2 = dt_c*(float)(500.0/1113.0),
                    a3 = dt_c*(float)(125.0/192.0), a4 = dt_c*(float)(-2187.0/6784.0),
                    a5 = dt_c*(float)(11.0/84.0);
        float yi0 = fmaf(a5, ks[5][0], fmaf(a4, ks[4][0], fmaf(a3, ks[3][0], fmaf(a2, ks[2][0], fmaf(a0, ks[0][0], y0)))));
        float yi1 = fmaf(a5, ks[5][1], fmaf(a4, ks[4][1], fmaf(a3, ks[3][1], fmaf(a2, ks[2][1], fmaf(a0, ks[0][1], y1)))));
        float yi2 = fmaf(a5, ks[5][2], fmaf(a4, ks[4][2], fmaf(a3, ks[3][2], fmaf(a2, ks[2][2], fmaf(a0, ks[0][2], y2)))));
        feval(t + dt_c, yi0, yi1, yi2, ks[6]); }

    // ---- 5th-order solution + embedded error ----
    const float db0 = dt_c*(float)(35.0/384.0), db2 = dt_c*(float)(500.0/1113.0),
                db3 = dt_c*(float)(125.0/192.0), db4 = dt_c*(float)(-2187.0/6784.0),
                db5 = dt_c*(float)(11.0/84.0);
    float y5_0 = fmaf(db5, ks[5][0], fmaf(db4, ks[4][0], fmaf(db3, ks[3][0], fmaf(db2, ks[2][0], fmaf(db0, ks[0][0], y0)))));
    float y5_1 = fmaf(db5, ks[5][1], fmaf(db4, ks[4][1], fmaf(db3, ks[3][1], fmaf(db2, ks[2][1], fmaf(db0, ks[0][1], y1)))));
    float y5_2 = fmaf(db5, ks[5][2], fmaf(db4, ks[4][2], fmaf(db3, ks[3][2], fmaf(db2, ks[2][2], fmaf(db0, ks[0][2], y2)))));

    const float de0 = dt_c*(float)(35.0/384.0   - 5179.0/57600.0);
    const float de2 = dt_c*(float)(500.0/1113.0 - 7571.0/16695.0);
    const float de3 = dt_c*(float)(125.0/192.0  - 393.0/640.0);
    const float de4 = dt_c*(float)(-2187.0/6784.0 + 92097.0/339200.0);
    const float de5 = dt_c*(float)(11.0/84.0    - 187.0/2100.0);
    const float de6 = dt_c*(float)(-1.0/40.0);
    float e_0 = fmaf(de6, ks[6][0], fmaf(de5, ks[5][0], fmaf(de4, ks[4][0], fmaf(de3, ks[3][0], fmaf(de2, ks[2][0], de0*ks[0][0])))));
    float e_1 = fmaf(de6, ks[6][1], fmaf(de5, ks[5][1], fmaf(de4, ks[4][1], fmaf(de3, ks[3][1], fmaf(de2, ks[2][1], de0*ks[0][1])))));
    float e_2 = fmaf(de6, ks[6][2], fmaf(de5, ks[5][2], fmaf(de4, ks[4][2], fmaf(de3, ks[3][2], fmaf(de2, ks[2][2], de0*ks[0][2])))));

    float e2 = 0.f;
    {   float tol = fmaf(1e-5f, fmaxf(fabsf(y0), fabsf(y5_0)), 1e-5f); float r = e_0/tol; e2 = fmaf(r,r,e2); }
    {   float tol = fmaf(1e-5f, fmaxf(fabsf(y1), fabsf(y5_1)), 1e-5f); float r = e_1/tol; e2 = fmaf(r,r,e2); }
    {   float tol = fmaf(1e-5f, fmaxf(fabsf(y2), fabsf(y5_2)), 1e-5f); float r = e_2/tol; e2 = fmaf(r,r,e2); }

    // block error sum: fixed butterfly tree (lane = point, identical in all 4 waves)
    float es = e2;
    es += __shfl_xor(es, 1);  es += __shfl_xor(es, 2);  es += __shfl_xor(es, 4);
    es += __shfl_xor(es, 8);  es += __shfl_xor(es, 16); es += __shfl_xor(es, 32);

    if (tid < 64) {
        Y0[3*gp+0] = y0;   Y0[3*gp+1] = y1;   Y0[3*gp+2] = y2;
        Y1[3*gp+0] = y5_0; Y1[3*gp+1] = y5_1; Y1[3*gp+2] = y5_2;
    }
    if (tid == 0) {
        part[blockIdx.x] = es;
        __threadfence();
        int old = __hip_atomic_fetch_add(&cnt[step], 1, __ATOMIC_ACQ_REL, __HIP_MEMORY_SCOPE_AGENT);
        islast_s = (old == NBLK - 1) ? 1 : 0;
    }
    __syncthreads();
    if (islast_s) {            // last-arriving block does the controller
        float v = __hip_atomic_load(&part[tid],       __ATOMIC_RELAXED, __HIP_MEMORY_SCOPE_AGENT)
                + __hip_atomic_load(&part[tid + 256], __ATOMIC_RELAXED, __HIP_MEMORY_SCOPE_AGENT);
        cs[tid] = v;
        __syncthreads();
        for (int off = 128; off > 0; off >>= 1) {
            if (tid < off) cs[tid] += cs[tid + off];
            __syncthreads();
        }
        if (tid == 0) {
            float err = sqrtf(cs[0] / (float)(NPTS * 3));
            err = fmaxf(err, 1e-10f);
            const bool accept = (err <= 1.0f);
            const float factor = fminf(fmaxf(0.9f * __powf(err, -0.2f), 0.2f), 10.0f);
            const float tn  = accept ? (t + dt_c) : t;
            float* o = flags + 4*(step + 1);
            o[0] = tn; o[1] = dt_c * factor;
            o[2] = accept ? 1.f : 0.f;
            o[3] = ((1.0f - tn) > 1e-9f) ? 1.f : 0.f;
        }
    }
}

__global__ void __launch_bounds__(256)
final_kernel(const float* __restrict__ flags,
             const float* __restrict__ Y0, const float* __restrict__ Y1,
             float* __restrict__ out)
{
    const int i = (int)blockIdx.x * 256 + (int)threadIdx.x;
    if (i < N3) {
        const bool acc = (flags[4*MAXSTEPS + 2] != 0.0f);
        out[i] = acc ? Y1[i] : Y0[i];
    }
}

extern "C" void kernel_launch(void* const* d_in, const int* in_sizes, int n_in,
                              void* d_out, int out_size, void* d_ws, size_t ws_size,
                              hipStream_t stream) {
    const float* y  = (const float*)d_in[0];
    const float* W1 = (const float*)d_in[1];
    const float* b1 = (const float*)d_in[2];
    const float* W2 = (const float*)d_in[3];
    const float* b2 = (const float*)d_in[4];
    const float* W3 = (const float*)d_in[5];
    const float* b3 = (const float*)d_in[6];

    float* ws    = (float*)d_ws;
    float* part  = ws;                 // [0, 512)
    float* flags = ws + 512;           // [512, 612)
    int*   cnt   = (int*)(ws + 640);   // [640, 664)
    float* Y0    = ws + 1024;
    float* Y1;
    const size_t need_full = (size_t)(1024 + 2*(size_t)N3) * sizeof(float);
    if (ws_size >= need_full) Y1 = Y0 + N3;
    else                      Y1 = (float*)d_out;

    // zero flags + counters (ws is re-poisoned 0xAA before every timed launch)
    hipMemsetAsync(ws + 512, 0, (672 - 512) * sizeof(float), stream);

    for (int s = 0; s < MAXSTEPS; ++s) {
        step_kernel<<<dim3(NBLK), dim3(256), 0, stream>>>(
            s, y, W1, b1, W2, b2, W3, b3, Y0, Y1, part, flags, cnt);
    }
    final_kernel<<<dim3((N3 + 255) / 256), dim3(256), 0, stream>>>(
        flags, Y0, Y1, (float*)d_out);
}

// Round 4
// 227.255 us; speedup vs baseline: 99.7933x; 1.0070x over previous
//
#include <hip/hip_runtime.h>

#define NPTS 32768
#define NBLK 512
#define MAXSTEPS 24
#define N3 (NPTS*3)

typedef __attribute__((ext_vector_type(8))) short short8;
typedef __attribute__((ext_vector_type(4))) float f32x4;
union U8 { uint4 v; short8 s; };
union F4 { uint4 v; float f[4]; };

__device__ __forceinline__ float fast_tanh(float x) {
    float e = __expf(2.0f * x);
    return fmaf(-2.0f, __builtin_amdgcn_rcpf(1.0f + e), 1.0f);
}
__device__ __forceinline__ uint32_t bf16_rne(float x) {
    uint32_t u = __float_as_uint(x);
    return (u + 0x7FFFu + ((u >> 16) & 1u)) >> 16;
}
__device__ __forceinline__ uint32_t hi16f(float x) { return __float_as_uint(x) >> 16; }
__device__ __forceinline__ uint32_t lo16f(float x) {
    uint32_t hu = __float_as_uint(x) & 0xFFFF0000u;
    return bf16_rne(x - __uint_as_float(hu));
}
__device__ __forceinline__ void split_pair(float x0, float x1, uint32_t& hw, uint32_t& lw) {
    uint32_t u0 = __float_as_uint(x0), u1 = __float_as_uint(x1);
    float l0 = x0 - __uint_as_float(u0 & 0xFFFF0000u);
    float l1 = x1 - __uint_as_float(u1 & 0xFFFF0000u);
    hw = (u0 >> 16) | (u1 & 0xFFFF0000u);
    lw = bf16_rne(l0) | (bf16_rne(l1) << 16);
}

// ---- param block: per lane (0..63), 36 uint4 chunks, layout chunk c at pv[c*64+lane]
//  c 0..3   : pw1[a]      layer-1 A-frag (W1 hi/lo in k-slots, b1 in k12/13)
//  c 4..11  : w2h[a][h]   (idx = 4 + 2a + h)
//  c 12..19 : w2l[a][h]
//  c 20..23 : b2v[a][r]
//  c 24..35 : w3f[a][12]  (3 chunks per a; w3f[a][3r+d] = W3[n(a,r)][d])
__global__ void __launch_bounds__(256)
init_params(const float* __restrict__ W1, const float* __restrict__ b1,
            const float* __restrict__ W2, const float* __restrict__ b2,
            const float* __restrict__ W3, float* __restrict__ pbase)
{
    const int lane = threadIdx.x & 63;
    const int w    = threadIdx.x >> 6;
    const int l15  = lane & 15;
    const int q    = (lane >> 4) & 3;
    uint4* pv = (uint4*)pbase;

    for (int c = w; c < 36; c += 4) {
        uint4 out;
        if (c < 4) {                       // pw1[a]: slots k=8q+j
            const int a = c, n = 16*a + l15;
            uint32_t s[8];
            #pragma unroll
            for (int j = 0; j < 8; ++j) {
                const int k = 8*q + j;
                uint32_t v = 0;
                if (k < 12) {
                    const int i = k / 3, r = k - 3*i;
                    const float wv = W1[i*64 + n];
                    v = (r == 2) ? lo16f(wv) : hi16f(wv);
                } else if (k == 12) v = hi16f(b1[n]);
                else if (k == 13)   v = lo16f(b1[n]);
                s[j] = v;
            }
            out = make_uint4(s[0]|(s[1]<<16), s[2]|(s[3]<<16), s[4]|(s[5]<<16), s[6]|(s[7]<<16));
        } else if (c < 20) {               // w2 frags
            const int idx = (c < 12) ? (c - 4) : (c - 12);
            const bool hi = (c < 12);
            const int a = idx >> 1, h = idx & 1, n = 16*a + l15;
            uint32_t d[4];
            #pragma unroll
            for (int j2 = 0; j2 < 4; ++j2) {
                const int k0 = 32*h + 8*q + 2*j2;
                const float w0 = W2[k0*64 + n], w1v = W2[(k0+1)*64 + n];
                d[j2] = hi ? (hi16f(w0) | (hi16f(w1v) << 16))
                           : (lo16f(w0) | (lo16f(w1v) << 16));
            }
            out = make_uint4(d[0], d[1], d[2], d[3]);
        } else if (c < 24) {               // b2v[a]
            const int a = c - 20;
            F4 f;
            #pragma unroll
            for (int r = 0; r < 4; ++r) f.f[r] = b2[16*a + 4*q + r];
            out = f.v;
        } else {                           // w3f
            const int a = (c - 24) / 3, pg = (c - 24) % 3;
            F4 f;
            #pragma unroll
            for (int e = 0; e < 4; ++e) {
                const int t = 4*pg + e, r = t / 3, d = t % 3;
                f.f[e] = W3[(16*a + 4*q + r)*3 + d];
            }
            out = f.v;
        }
        pv[c*64 + lane] = out;
    }
}

__global__ void __launch_bounds__(256, 2)
step_kernel(int step,
            const float* __restrict__ yin, const float* __restrict__ pbase,
            const float* __restrict__ b3,
            float* __restrict__ Y0, float* __restrict__ Y1,
            float* __restrict__ part, float* __restrict__ flags,
            int* __restrict__ cnt)
{
    // per-wave regions: 16 rows (points) x 36 dwords (64 bf16 + pad), hi/lo planes
    __shared__ uint32_t H1hi[4*576];
    __shared__ uint32_t H1lo[4*576];
    __shared__ float    cs4[4];

    const int tid  = threadIdx.x;
    const int lane = tid & 63;
    const int l15  = lane & 15;
    const int q    = (lane >> 4) & 3;
    const int w    = __builtin_amdgcn_readfirstlane(tid >> 6);
    const int wbase = w * 576;
    const int gp   = (int)blockIdx.x * 64 + 16*w + l15;   // this lane's state point

    float t, dt; bool accPrev, active;
    if (step == 0) { t = 0.f; dt = 0.05f; accPrev = false; active = true; }
    else {
        const float* fl = flags + 4*step;
        t = fl[0]; dt = fl[1]; accPrev = (fl[2] != 0.f); active = (fl[3] != 0.f);
    }

    if (!active) {                 // no-op step: commit pending accept once
        if (accPrev) {
            const int base3 = 3 * ((int)blockIdx.x * 64 + 16*w);
            if (lane < 48) Y0[base3 + lane] = Y1[base3 + lane];
        }
        return;
    }

    float y0, y1, y2;
    if (step == 0)    { y0 = yin[3*gp]; y1 = yin[3*gp+1]; y2 = yin[3*gp+2]; }
    else if (accPrev) { y0 = Y1[3*gp];  y1 = Y1[3*gp+1];  y2 = Y1[3*gp+2];  }
    else              { y0 = Y0[3*gp];  y1 = Y0[3*gp+1];  y2 = Y0[3*gp+2];  }

    const float dt_c = fminf(dt, 1.0f - t);

    // ---- load pre-split params (36 coalesced dwordx4) ----
    const uint4* pv = (const uint4*)pbase;
    short8 pw1[4], w2h[4][2], w2l[4][2];
    float b2v[4][4], w3f[4][12];
    #pragma unroll
    for (int a = 0; a < 4; ++a) { U8 u; u.v = pv[a*64 + lane]; pw1[a] = u.s; }
    #pragma unroll
    for (int a = 0; a < 4; ++a)
    #pragma unroll
    for (int h = 0; h < 2; ++h) {
        U8 u; u.v = pv[(4  + 2*a + h)*64 + lane]; w2h[a][h] = u.s;
        U8 l; l.v = pv[(12 + 2*a + h)*64 + lane]; w2l[a][h] = l.s;
    }
    #pragma unroll
    for (int a = 0; a < 4; ++a) {
        F4 f; f.v = pv[(20 + a)*64 + lane];
        #pragma unroll
        for (int r = 0; r < 4; ++r) b2v[a][r] = f.f[r];
    }
    #pragma unroll
    for (int a = 0; a < 4; ++a)
    #pragma unroll
    for (int pg = 0; pg < 3; ++pg) {
        F4 f; f.v = pv[(24 + 3*a + pg)*64 + lane];
        #pragma unroll
        for (int e = 0; e < 4; ++e) w3f[a][4*pg + e] = f.f[e];
    }
    const float b30 = b3[0], b31 = b3[1], b32s = b3[2];

    float ks[7][3];

    auto feval = [&](float ts, float yi0, float yi1, float yi2, float* kout) {
        // ---- layer-1 B-frag from registers (split y/t into k-slots) ----
        uint32_t y0h,y0l,y1h,y1l,y2h,y2l,th_,tl_;
        split_pair(yi0, yi0, y0h, y0l); y0h &= 0xFFFFu; y0l &= 0xFFFFu;
        split_pair(yi1, yi1, y1h, y1l); y1h &= 0xFFFFu; y1l &= 0xFFFFu;
        split_pair(yi2, yi2, y2h, y2l); y2h &= 0xFFFFu; y2l &= 0xFFFFu;
        split_pair(ts,  ts,  th_, tl_); th_ &= 0xFFFFu; tl_ &= 0xFFFFu;
        uint32_t bd0, bd1, bd2, bd3;
        if (q == 0)      { bd0 = y0h|(y0l<<16); bd1 = y0h|(y1h<<16);
                           bd2 = y1l|(y1h<<16); bd3 = y2h|(y2l<<16); }
        else if (q == 1) { bd0 = y2h|(th_<<16); bd1 = tl_|(th_<<16);
                           bd2 = 0x3F803F80u;   bd3 = 0u; }
        else             { bd0 = bd1 = bd2 = bd3 = 0u; }
        U8 B1; B1.v = make_uint4(bd0, bd1, bd2, bd3);

        const f32x4 zero4 = (f32x4)(0.0f);
        // ---- layer 1: 4 MFMAs; C-layout => lane holds h1[own point][16a+4q+r] ----
        float h1v[16];
        #pragma unroll
        for (int a = 0; a < 4; ++a) {
            f32x4 c = __builtin_amdgcn_mfma_f32_16x16x32_bf16(pw1[a], B1.s, zero4, 0, 0, 0);
            h1v[4*a+0] = fast_tanh(c[0]); h1v[4*a+1] = fast_tanh(c[1]);
            h1v[4*a+2] = fast_tanh(c[2]); h1v[4*a+3] = fast_tanh(c[3]);
        }
        // ---- split h1 and stage through LDS (wave-internal, no barrier) ----
        #pragma unroll
        for (int a = 0; a < 4; ++a) {
            uint32_t hA, lA, hB, lB;
            split_pair(h1v[4*a+0], h1v[4*a+1], hA, lA);
            split_pair(h1v[4*a+2], h1v[4*a+3], hB, lB);
            const int col = wbase + l15*36 + 8*a + 2*q;
            *(uint2*)&H1hi[col] = make_uint2(hA, hB);
            *(uint2*)&H1lo[col] = make_uint2(lA, lB);
        }
        const uint32_t* rh = &H1hi[wbase + l15*36 + 4*q];
        const uint32_t* rl = &H1lo[wbase + l15*36 + 4*q];
        U8 bh0, bh1, bl0, bl1;
        bh0.v = *(const uint4*)rh;        bh1.v = *(const uint4*)(rh + 16);
        bl0.v = *(const uint4*)rl;        bl1.v = *(const uint4*)(rl + 16);

        // ---- layer 2 (24 MFMAs) + fused layer 3 ----
        float po0 = 0.f, po1 = 0.f, po2 = 0.f;
        #pragma unroll
        for (int a = 0; a < 4; ++a) {
            f32x4 acc = zero4;
            acc = __builtin_amdgcn_mfma_f32_16x16x32_bf16(w2h[a][0], bh0.s, acc, 0, 0, 0);
            acc = __builtin_amdgcn_mfma_f32_16x16x32_bf16(w2h[a][1], bh1.s, acc, 0, 0, 0);
            acc = __builtin_amdgcn_mfma_f32_16x16x32_bf16(w2h[a][0], bl0.s, acc, 0, 0, 0);
            acc = __builtin_amdgcn_mfma_f32_16x16x32_bf16(w2h[a][1], bl1.s, acc, 0, 0, 0);
            acc = __builtin_amdgcn_mfma_f32_16x16x32_bf16(w2l[a][0], bh0.s, acc, 0, 0, 0);
            acc = __builtin_amdgcn_mfma_f32_16x16x32_bf16(w2l[a][1], bh1.s, acc, 0, 0, 0);
            #pragma unroll
            for (int r = 0; r < 4; ++r) {
                const float h2 = fast_tanh(acc[r] + b2v[a][r]);
                po0 = fmaf(h2, w3f[a][3*r+0], po0);
                po1 = fmaf(h2, w3f[a][3*r+1], po1);
                po2 = fmaf(h2, w3f[a][3*r+2], po2);
            }
        }
        // quad-reduce: neurons are spread across q; every lane ends with full k
        po0 += __shfl_xor(po0, 16); po0 += __shfl_xor(po0, 32);
        po1 += __shfl_xor(po1, 16); po1 += __shfl_xor(po1, 32);
        po2 += __shfl_xor(po2, 16); po2 += __shfl_xor(po2, 32);
        kout[0] = po0 + b30; kout[1] = po1 + b31; kout[2] = po2 + b32s;
    };

    // ---- 7 dopri5 stages ----
    feval(t, y0, y1, y2, ks[0]);
    {   const float a = dt_c * (float)(1.0/5.0);
        feval(fmaf((float)(1.0/5.0), dt_c, t),
              fmaf(a, ks[0][0], y0), fmaf(a, ks[0][1], y1), fmaf(a, ks[0][2], y2), ks[1]); }
    {   const float a0 = dt_c*(float)(3.0/40.0), a1 = dt_c*(float)(9.0/40.0);
        float yi0 = fmaf(a1, ks[1][0], fmaf(a0, ks[0][0], y0));
        float yi1 = fmaf(a1, ks[1][1], fmaf(a0, ks[0][1], y1));
        float yi2 = fmaf(a1, ks[1][2], fmaf(a0, ks[0][2], y2));
        feval(fmaf((float)(3.0/10.0), dt_c, t), yi0, yi1, yi2, ks[2]); }
    {   const float a0 = dt_c*(float)(44.0/45.0), a1 = dt_c*(float)(-56.0/15.0),
                    a2 = dt_c*(float)(32.0/9.0);
        float yi0 = fmaf(a2, ks[2][0], fmaf(a1, ks[1][0], fmaf(a0, ks[0][0], y0)));
        float yi1 = fmaf(a2, ks[2][1], fmaf(a1, ks[1][1], fmaf(a0, ks[0][1], y1)));
        float yi2 = fmaf(a2, ks[2][2], fmaf(a1, ks[1][2], fmaf(a0, ks[0][2], y2)));
        feval(fmaf((float)(4.0/5.0), dt_c, t), yi0, yi1, yi2, ks[3]); }
    {   const float a0 = dt_c*(float)(19372.0/6561.0), a1 = dt_c*(float)(-25360.0/2187.0),
                    a2 = dt_c*(float)(64448.0/6561.0), a3 = dt_c*(float)(-212.0/729.0);
        float yi0 = fmaf(a3, ks[3][0], fmaf(a2, ks[2][0], fmaf(a1, ks[1][0], fmaf(a0, ks[0][0], y0))));
        float yi1 = fmaf(a3, ks[3][1], fmaf(a2, ks[2][1], fmaf(a1, ks[1][1], fmaf(a0, ks[0][1], y1))));
        float yi2 = fmaf(a3, ks[3][2], fmaf(a2, ks[2][2], fmaf(a1, ks[1][2], fmaf(a0, ks[0][2], y2))));
        feval(fmaf((float)(8.0/9.0), dt_c, t), yi0, yi1, yi2, ks[4]); }
    {   const float a0 = dt_c*(float)(9017.0/3168.0), a1 = dt_c*(float)(-355.0/33.0),
                    a2 = dt_c*(float)(46732.0/5247.0), a3 = dt_c*(float)(49.0/176.0),
                    a4 = dt_c*(float)(-5103.0/18656.0);
        float yi0 = fmaf(a4, ks[4][0], fmaf(a3, ks[3][0], fmaf(a2, ks[2][0], fmaf(a1, ks[1][0], fmaf(a0, ks[0][0], y0)))));
        float yi1 = fmaf(a4, ks[4][1], fmaf(a3, ks[3][1], fmaf(a2, ks[2][1], fmaf(a1, ks[1][1], fmaf(a0, ks[0][1], y1)))));
        float yi2 = fmaf(a4, ks[4][2], fmaf(a3, ks[3][2], fmaf(a2, ks[2][2], fmaf(a1, ks[1][2], fmaf(a0, ks[0][2], y2)))));
        feval(t + dt_c, yi0, yi1, yi2, ks[5]); }
    {   const float a0 = dt_c*(float)(35.0/384.0), a2 = dt_c*(float)(500.0/1113.0),
                    a3 = dt_c*(float)(125.0/192.0), a4 = dt_c*(float)(-2187.0/6784.0),
                    a5 = dt_c*(float)(11.0/84.0);
        float yi0 = fmaf(a5, ks[5][0], fmaf(a4, ks[4][0], fmaf(a3, ks[3][0], fmaf(a2, ks[2][0], fmaf(a0, ks[0][0], y0)))));
        float yi1 = fmaf(a5, ks[5][1], fmaf(a4, ks[4][1], fmaf(a3, ks[3][1], fmaf(a2, ks[2][1], fmaf(a0, ks[0][1], y1)))));
        float yi2 = fmaf(a5, ks[5][2], fmaf(a4, ks[4][2], fmaf(a3, ks[3][2], fmaf(a2, ks[2][2], fmaf(a0, ks[0][2], y2)))));
        feval(t + dt_c, yi0, yi1, yi2, ks[6]); }

    // ---- 5th-order solution + embedded error ----
    const float db0 = dt_c*(float)(35.0/384.0), db2 = dt_c*(float)(500.0/1113.0),
                db3 = dt_c*(float)(125.0/192.0), db4 = dt_c*(float)(-2187.0/6784.0),
                db5 = dt_c*(float)(11.0/84.0);
    float y5_0 = fmaf(db5, ks[5][0], fmaf(db4, ks[4][0], fmaf(db3, ks[3][0], fmaf(db2, ks[2][0], fmaf(db0, ks[0][0], y0)))));
    float y5_1 = fmaf(db5, ks[5][1], fmaf(db4, ks[4][1], fmaf(db3, ks[3][1], fmaf(db2, ks[2][1], fmaf(db0, ks[0][1], y1)))));
    float y5_2 = fmaf(db5, ks[5][2], fmaf(db4, ks[4][2], fmaf(db3, ks[3][2], fmaf(db2, ks[2][2], fmaf(db0, ks[0][2], y2)))));

    const float de0 = dt_c*(float)(35.0/384.0   - 5179.0/57600.0);
    const float de2 = dt_c*(float)(500.0/1113.0 - 7571.0/16695.0);
    const float de3 = dt_c*(float)(125.0/192.0  - 393.0/640.0);
    const float de4 = dt_c*(float)(-2187.0/6784.0 + 92097.0/339200.0);
    const float de5 = dt_c*(float)(11.0/84.0    - 187.0/2100.0);
    const float de6 = dt_c*(float)(-1.0/40.0);
    float e_0 = fmaf(de6, ks[6][0], fmaf(de5, ks[5][0], fmaf(de4, ks[4][0], fmaf(de3, ks[3][0], fmaf(de2, ks[2][0], de0*ks[0][0])))));
    float e_1 = fmaf(de6, ks[6][1], fmaf(de5, ks[5][1], fmaf(de4, ks[4][1], fmaf(de3, ks[3][1], fmaf(de2, ks[2][1], de0*ks[0][1])))));
    float e_2 = fmaf(de6, ks[6][2], fmaf(de5, ks[5][2], fmaf(de4, ks[4][2], fmaf(de3, ks[3][2], fmaf(de2, ks[2][2], de0*ks[0][2])))));

    float e2 = 0.f;
    {   float tol = fmaf(1e-5f, fmaxf(fabsf(y0), fabsf(y5_0)), 1e-5f); float r = e_0/tol; e2 = fmaf(r,r,e2); }
    {   float tol = fmaf(1e-5f, fmaxf(fabsf(y1), fabsf(y5_1)), 1e-5f); float r = e_1/tol; e2 = fmaf(r,r,e2); }
    {   float tol = fmaf(1e-5f, fmaxf(fabsf(y2), fabsf(y5_2)), 1e-5f); float r = e_2/tol; e2 = fmaf(r,r,e2); }

    if (q == 0) {   // one replica per point stores state
        Y0[3*gp+0] = y0;   Y0[3*gp+1] = y1;   Y0[3*gp+2] = y2;
        Y1[3*gp+0] = y5_0; Y1[3*gp+1] = y5_1; Y1[3*gp+2] = y5_2;
    }

    // per-wave error sum (points replicated across quads -> sum within 16-lane group)
    float es = e2;
    es += __shfl_xor(es, 1); es += __shfl_xor(es, 2);
    es += __shfl_xor(es, 4); es += __shfl_xor(es, 8);
    if (lane == 0) cs4[w] = es;
    __syncthreads();               // the ONLY barrier in an active step

    if (w == 0) {
        int old = 0;
        if (lane == 0) {
            part[blockIdx.x] = (cs4[0] + cs4[1]) + (cs4[2] + cs4[3]);
            __threadfence();
            old = __hip_atomic_fetch_add(&cnt[step], 1, __ATOMIC_ACQ_REL, __HIP_MEMORY_SCOPE_AGENT);
        }
        old = __shfl(old, 0);
        if (old == NBLK - 1) {     // last-arriving block: controller (one wave)
            float v = 0.f;
            #pragma unroll
            for (int j = 0; j < 8; ++j)
                v += __hip_atomic_load(&part[lane + 64*j], __ATOMIC_RELAXED, __HIP_MEMORY_SCOPE_AGENT);
            v += __shfl_xor(v, 1);  v += __shfl_xor(v, 2);  v += __shfl_xor(v, 4);
            v += __shfl_xor(v, 8);  v += __shfl_xor(v, 16); v += __shfl_xor(v, 32);
            if (lane == 0) {
                float err = sqrtf(v / (float)N3);
                err = fmaxf(err, 1e-10f);
                const bool accept = (err <= 1.0f);
                const float factor = fminf(fmaxf(0.9f * __powf(err, -0.2f), 0.2f), 10.0f);
                const float tn = accept ? (t + dt_c) : t;
                float* o = flags + 4*(step + 1);
                o[0] = tn; o[1] = dt_c * factor;
                o[2] = accept ? 1.f : 0.f;
                o[3] = ((1.0f - tn) > 1e-9f) ? 1.f : 0.f;
            }
        }
    }
}

__global__ void __launch_bounds__(256)
commit_kernel(const float* __restrict__ flags,
              const float* __restrict__ Y1, float* __restrict__ out)
{
    const int i = (int)blockIdx.x * 256 + (int)threadIdx.x;
    if (i < N3 && flags[4*MAXSTEPS + 2] != 0.0f) out[i] = Y1[i];
}

extern "C" void kernel_launch(void* const* d_in, const int* in_sizes, int n_in,
                              void* d_out, int out_size, void* d_ws, size_t ws_size,
                              hipStream_t stream) {
    const float* y  = (const float*)d_in[0];
    const float* W1 = (const float*)d_in[1];
    const float* b1 = (const float*)d_in[2];
    const float* W2 = (const float*)d_in[3];
    const float* b2 = (const float*)d_in[4];
    const float* W3 = (const float*)d_in[5];
    const float* b3 = (const float*)d_in[6];

    float* ws    = (float*)d_ws;
    float* part  = ws;                    // [0, 512)
    float* flags = ws + 2048;             // [2048, 2148): 25 slots x 4
    int*   cnt   = (int*)(ws + 2176);     // [2176, 2200)
    float* Y1    = ws + 4096;             // [4096, 4096+N3)
    float* pbase = ws + 4096 + N3;        // 36*64*4 = 9216 floats
    float* Y0    = (float*)d_out;         // committed state lives in d_out

    init_params<<<dim3(1), dim3(256), 0, stream>>>(W1, b1, W2, b2, W3, pbase);
    hipMemsetAsync(ws + 2048, 0, 256 * sizeof(float), stream);   // flags + cnt

    for (int s = 0; s < MAXSTEPS; ++s) {
        step_kernel<<<dim3(NBLK), dim3(256), 0, stream>>>(
            s, y, pbase, b3, Y0, Y1, part, flags, cnt);
    }
    commit_kernel<<<dim3((N3 + 255) / 256), dim3(256), 0, stream>>>(
        flags, Y1, (float*)d_out);
}